// Round 12
// baseline (168.135 us; speedup 1.0000x reference)
//
#include <hip/hip_runtime.h>
#include <hip/hip_bf16.h>

// Modulated conv2d (StyleGAN2) on MI355X.
// out[b,o] = rsig[b,o] * conv(s[b,:]*x[b,:], W*SCALE)   (shared weights)
// rsig[b,o] = 1/sqrt(sum_i s[b,i]^2 * wsq[o,i] + 1e-8)
// Conv as implicit GEMM: D[o][p] = sum_k Wb[o][k] * Xcl[p][k].
//
// R12 = R6 conv (z-split K, 512 blk = 2/CU, 256 thr, 4 waves 2Mx2N, per-wave
// 64x128, 2x __syncthreads loop) with A REMOVED FROM LDS:
//  - pack_w emits wAf fragment-packed [kt][oblk][wr][mi][kk][lane][8] ->
//    per tile a wave loads its 8 A-frags as 8 coalesced 1KB dwordx4 loads,
//    ping-pong aP/aQ (static indexing), prefetched 1 tile ahead under MFMA.
//    Default x-major dispatch: 64 consecutive blocks share a 590KB A
//    half-panel -> L2-resident per XCD (unlike R3's swizzled full-K fiasco).
//  - LDS = B only (32KB single buffer, R6's row-major + XOR swizzle + 128B-
//    contiguous staging, 0 conflicts measured R1-R11).
//  - per block-tile: LDS reads 96->64 b128 (-28K cyc/CU), DMA writes -9K.
// Tail = R10 verified: halo-zero, bf16 partials both z, merge2 (ws fallback).

typedef __attribute__((ext_vector_type(4))) float f32x4;
typedef __attribute__((ext_vector_type(8))) short bf16x8;

#define NB    16
#define CIN   512
#define COUT  512
#define KTOT  4608           // CIN * 9
#define NPIX  (NB * 32 * 32) // 16384

__device__ __forceinline__ void gload_lds16(const void* g, void* l) {
  __builtin_amdgcn_global_load_lds(
      (__attribute__((address_space(1))) void*)(g),
      (__attribute__((address_space(3))) void*)(l), 16, 0, 0);
}

__device__ __forceinline__ float bf16bits_to_f32(short v) {
  return __uint_as_float(((unsigned)(unsigned short)v) << 16);
}

// ---- kernel 1: pack weights into per-wave fragment order + wsq ----
// wAf element for (o, kg=tap*512+ci):
//   kt=kg>>6, kp=kg&63, kk=kp>>5, lane=(o&15)|(((kp>>3)&3)<<4), j=kp&7,
//   mi=(o>>4)&3, wr=(o>>6)&1, ob=o>>7
//   addr = ((kt*8 + ob*2 + wr) << 12) + ((mi*2+kk) << 9) + (lane<<3) + j
__global__ __launch_bounds__(256) void pack_w_kernel(
    const float* __restrict__ w, __hip_bfloat16* __restrict__ wAf,
    float* __restrict__ wsq) {
  const int idx = blockIdx.x * 256 + threadIdx.x;   // = o*512 + ci
  const int o = idx >> 9, ci = idx & 511;
  const float* wp = w + (size_t)idx * 9;
  const float WSCALE = 0.014731391274719739f;       // 1/sqrt(512*9)
  const int mi = (o >> 4) & 3, wr = (o >> 6) & 1, ob = o >> 7;
  float sum = 0.f;
#pragma unroll
  for (int t = 0; t < 9; ++t) {
    float v = wp[t] * WSCALE;
    sum += v * v;
    const int kg = t * 512 + ci;
    const int kt = kg >> 6, kp = kg & 63;
    const int kk = kp >> 5;
    const int lane = (o & 15) | (((kp >> 3) & 3) << 4);
    wAf[(((size_t)(kt * 8 + ob * 2 + wr)) << 12) +
        (((mi << 1) | kk) << 9) + (lane << 3) + (kp & 7)] =
        __float2bfloat16(v);
  }
  wsq[idx] = sum;
}

// ---- kernel 2: rsig[b][o], one wave per (b,o) ----
__global__ __launch_bounds__(256) void calc_rsig_kernel(
    const float* __restrict__ s, const float* __restrict__ wsq,
    float* __restrict__ rsig) {
  const int wid = blockIdx.x * 4 + (threadIdx.x >> 6); // b*512 + o
  const int lane = threadIdx.x & 63;
  const int b = wid >> 9, o = wid & 511;
  const float* sp = s + b * 512;
  const float* wp = wsq + o * 512;
  float sum = 0.f;
#pragma unroll
  for (int i = 0; i < 8; ++i) {
    float sv = sp[lane + i * 64];
    sum += sv * sv * wp[lane + i * 64];
  }
#pragma unroll
  for (int off = 32; off > 0; off >>= 1) sum += __shfl_down(sum, off, 64);
  if (lane == 0) rsig[wid] = 1.0f / sqrtf(sum + 1e-8f);
}

// ---- kernel 3: modulate + NCHW -> padded channels-last bf16 ----
__global__ __launch_bounds__(256) void modulate_kernel(
    const float* __restrict__ x, const float* __restrict__ s,
    __hip_bfloat16* __restrict__ xpad) {
  const int by = blockIdx.x;            // b*32 + y
  const int b = by >> 5, y = by & 31;
  __shared__ __attribute__((aligned(16))) __hip_bfloat16 tile[32][72];
  const int tid = threadIdx.x;
  const int xc = tid & 31;
  const int cr0 = tid >> 5;
  const float* xrow = x + ((size_t)b * 512 * 32 + y) * 32;
  const float* sb = s + b * 512;
  __hip_bfloat16* orow = xpad + (size_t)((b * 34 + y + 1) * 34) * 512;

  for (int ci0 = 0; ci0 < 512; ci0 += 64) {
#pragma unroll
    for (int r = 0; r < 8; ++r) {
      const int cir = r * 8 + cr0;
      const int ci = ci0 + cir;
      float v = xrow[(size_t)ci * 1024 + xc] * sb[ci];
      tile[xc][cir] = __float2bfloat16(v);
    }
    __syncthreads();
    const int xcw = tid >> 3, vec = tid & 7;
    bf16x8 v = *(const bf16x8*)&tile[xcw][vec * 8];
    *(bf16x8*)(orow + (size_t)(xcw + 1) * 512 + ci0 + vec * 8) = v;
    __syncthreads();
  }
}

// ---- kernel 3b: zero only the halo of xpad ----
__global__ __launch_bounds__(256) void halo_zero_kernel(
    __hip_bfloat16* __restrict__ xpad) {
  const int sb = blockIdx.x;           // b*132 + site
  const int b = sb / 132, s = sb - b * 132;
  int y, x;
  if (s < 34)       { y = 0;        x = s; }
  else if (s < 68)  { y = 33;       x = s - 34; }
  else if (s < 100) { y = s - 67;   x = 0; }
  else              { y = s - 99;   x = 33; }
  unsigned* p = (unsigned*)(xpad + (size_t)((b * 34 + y) * 34 + x) * 512);
  p[threadIdx.x] = 0u;   // 256 x 4B = 512 bf16
}

// ---- kernel 4: implicit-GEMM conv, A in registers, B-only LDS ----
// Per BODY(kt): stage B(kt) 8x gload_lds | sync | prefetch A(kt+1)->regs |
// {2 k-halves x 2 n-quads: read bv[4], 16 MFMA} | sync.
#define BODY(KT, AU, AN)                                                      \
  {                                                                           \
    const int ktg_ = zbase + (KT);                                            \
    {                                                                         \
      const int tap = ktg_ >> 3;                                              \
      const int xoff = (tap + 31 * (tap / 3)) * 512 + ((ktg_ & 7) << 6);      \
      _Pragma("unroll")                                                       \
      for (int r = 0; r < 8; ++r)                                             \
        gload_lds16(xpad + (size_t)(gB[r] + xoff),                            \
                    ldsB + (r * 256 + tid) * 16);                             \
    }                                                                         \
    __syncthreads();                                                          \
    if ((KT) + 1 < 36) {                                                      \
      const __hip_bfloat16* aw = awBase + ((size_t)(ktg_ + 1) << 15);         \
      _Pragma("unroll")                                                       \
      for (int f = 0; f < 8; ++f)                                             \
        AN[f] = *(const bf16x8*)(aw + (f << 9));                              \
    }                                                                         \
    _Pragma("unroll")                                                         \
    for (int half = 0; half < 2; ++half) {                                    \
      const int kb = (half << 6) | kb0;                                       \
      _Pragma("unroll")                                                       \
      for (int nq = 0; nq < 2; ++nq) {                                        \
        bf16x8 bv[4];                                                         \
        _Pragma("unroll")                                                     \
        for (int nn = 0; nn < 4; ++nn) {                                      \
          const int row = (wc << 7) + (((nq << 2) | nn) << 4) + l15;          \
          bv[nn] = *(const bf16x8*)(ldsB + row * 128 +                        \
                                    (kb ^ ((row & 7) << 4)));                 \
        }                                                                     \
        __builtin_amdgcn_s_setprio(1);                                        \
        _Pragma("unroll")                                                     \
        for (int mi = 0; mi < 4; ++mi)                                        \
          _Pragma("unroll")                                                   \
          for (int nn = 0; nn < 4; ++nn)                                      \
            acc[mi][(nq << 2) | nn] = __builtin_amdgcn_mfma_f32_16x16x32_bf16(\
                AU[(mi << 1) | half], bv[nn], acc[mi][(nq << 2) | nn],        \
                0, 0, 0);                                                     \
        __builtin_amdgcn_s_setprio(0);                                        \
      }                                                                       \
    }                                                                         \
    __syncthreads();                                                          \
  }

__global__ __launch_bounds__(256, 2) void conv_gemm_kernel(
    const __hip_bfloat16* __restrict__ wAf,   // fragment-packed, 4.7MB
    const __hip_bfloat16* __restrict__ xpad,  // [16][34][34][512]
    const float* __restrict__ rsig,           // [16][512]
    float* __restrict__ out,                  // f32 out (fallback, z=0)
    __hip_bfloat16* __restrict__ p0,          // bf16 partial z=0 (or null)
    __hip_bfloat16* __restrict__ p1) {        // bf16 partial z=1
  __shared__ __attribute__((aligned(16))) char ldsB[32768];

  const int tid = threadIdx.x;
  const int wv = tid >> 6, lane = tid & 63, l15 = lane & 15;
  const int bo0 = blockIdx.y << 7;   // cout block (128)
  const int bp0 = blockIdx.x << 8;   // pixel block (256; 256 | 1024 per image)
  const int z = blockIdx.z;          // K-half (ktg zbase..zbase+35)
  const int zbase = z * 36;
  const int bimg = blockIdx.x >> 2;
  const int wr = wv >> 1, wc = wv & 1;
  const int kb0 = (lane >> 4) << 4;

  // B staging source offsets (pre-swizzled chunk within row; rule 21).
  int gB[8];
#pragma unroll
  for (int r = 0; r < 8; ++r) {
    const int c = r * 256 + tid, row = c >> 3, sc = (c & 7) ^ (row & 7);
    const int p = bp0 + row, b = p >> 10, rem = p & 1023, y = rem >> 5,
              xx = rem & 31;
    gB[r] = ((b * 34 + y) * 34 + xx) * 512 + sc * 8;
  }

  // A fragment base: frag (mi,kk) of tile ktg at
  //   awBase + (ktg<<15) + ((mi*2+kk)<<9)   (elements), +lane*8 folded in.
  const __hip_bfloat16* awBase =
      wAf + (((size_t)(blockIdx.y * 2 + wr)) << 12) + (lane << 3);

  f32x4 acc[4][8];
#pragma unroll
  for (int mi = 0; mi < 4; ++mi)
#pragma unroll
    for (int ni = 0; ni < 8; ++ni) acc[mi][ni] = f32x4{0.f, 0.f, 0.f, 0.f};

  bf16x8 aP[8], aQ[8];
  {  // preload A(tile zbase)
    const __hip_bfloat16* aw = awBase + ((size_t)zbase << 15);
#pragma unroll
    for (int f = 0; f < 8; ++f) aP[f] = *(const bf16x8*)(aw + (f << 9));
  }

#pragma unroll 1
  for (int kt = 0; kt < 36; kt += 2) {
    BODY(kt, aP, aQ);
    BODY(kt + 1, aQ, aP);
  }

  // Epilogue: scale by rsig; bf16 partial per z (f32 fallback if p0==null).
  // C/D: col(=p)=lane&15, row(=o)=(lane>>4)*4+r
  __hip_bfloat16* pz = z ? p1 : p0;
  const bool f32path = (p0 == nullptr) && (z == 0);
#pragma unroll
  for (int mi = 0; mi < 4; ++mi) {
    const int o = bo0 + (wr << 6) + (mi << 4) + ((lane >> 4) << 2);
    const f32x4 rs = *(const f32x4*)(rsig + (bimg << 9) + o);
#pragma unroll
    for (int ni = 0; ni < 8; ++ni) {
      const int p = bp0 + (wc << 7) + (ni << 4) + l15;
      const int prem = p & 1023;
#pragma unroll
      for (int r = 0; r < 4; ++r) {
        const float v = acc[mi][ni][r] * rs[r];
        const size_t oidx = ((size_t)((bimg << 9) + o + r)) * 1024 + prem;
        if (f32path) out[oidx] = v;
        else pz[oidx] = __float2bfloat16(v);
      }
    }
  }
}

// ---- kernel 5a: merge out = p0 + p1 ----
__global__ __launch_bounds__(256) void merge2_kernel(
    float* __restrict__ out, const __hip_bfloat16* __restrict__ p0,
    const __hip_bfloat16* __restrict__ p1) {
  const size_t i = (size_t)blockIdx.x * 256 + threadIdx.x;
  const bf16x8 a = ((const bf16x8*)p0)[i];
  const bf16x8 b = ((const bf16x8*)p1)[i];
  f32x4 o0, o1;
#pragma unroll
  for (int j = 0; j < 4; ++j) {
    o0[j] = bf16bits_to_f32(a[j]) + bf16bits_to_f32(b[j]);
    o1[j] = bf16bits_to_f32(a[4 + j]) + bf16bits_to_f32(b[4 + j]);
  }
  ((f32x4*)out)[2 * i] = o0;
  ((f32x4*)out)[2 * i + 1] = o1;
}

// ---- kernel 5b: fallback merge out += p1 ----
__global__ __launch_bounds__(256) void merge1_kernel(
    float* __restrict__ out, const __hip_bfloat16* __restrict__ p1) {
  const size_t i = (size_t)blockIdx.x * 256 + threadIdx.x;
  f32x4* o4 = (f32x4*)out + 2 * i;
  f32x4 a = o4[0], b = o4[1];
  const bf16x8 pv = ((const bf16x8*)p1)[i];
#pragma unroll
  for (int j = 0; j < 4; ++j) {
    a[j] += bf16bits_to_f32(pv[j]);
    b[j] += bf16bits_to_f32(pv[4 + j]);
  }
  o4[0] = a;
  o4[1] = b;
}

extern "C" void kernel_launch(void* const* d_in, const int* in_sizes, int n_in,
                              void* d_out, int out_size, void* d_ws,
                              size_t ws_size, hipStream_t stream) {
  const float* x = (const float*)d_in[0];   // [16,512,32,32]
  const float* s = (const float*)d_in[1];   // [16,512]
  const float* w = (const float*)d_in[2];   // [512,512,3,3]
  float* out = (float*)d_out;               // [16,512,32,32] f32

  char* ws = (char*)d_ws;
  const size_t xpad_bytes = (size_t)NB * 34 * 34 * 512 * 2;  // 18,939,904
  const size_t wA_bytes = (size_t)COUT * KTOT * 2;           //  4,718,592
  const size_t wsq_bytes = (size_t)COUT * CIN * 4;           //  1,048,576
  const size_t rsig_bytes = (size_t)NB * COUT * 4;           //     32,768
  const size_t part_bytes = (size_t)NPIX * COUT * 2;         // 16,777,216
  __hip_bfloat16* xpad = (__hip_bfloat16*)ws;
  __hip_bfloat16* wAf = (__hip_bfloat16*)(ws + xpad_bytes);
  float* wsq = (float*)(ws + xpad_bytes + wA_bytes);
  float* rsig = (float*)(ws + xpad_bytes + wA_bytes + wsq_bytes);
  char* pbase = ws + xpad_bytes + wA_bytes + wsq_bytes + rsig_bytes;
  __hip_bfloat16* p1 = (__hip_bfloat16*)pbase;
  __hip_bfloat16* p0 = (__hip_bfloat16*)(pbase + part_bytes);
  const bool two_partials =
      ws_size >= (xpad_bytes + wA_bytes + wsq_bytes + rsig_bytes +
                  2 * part_bytes);

  halo_zero_kernel<<<NB * 132, 256, 0, stream>>>(xpad);
  pack_w_kernel<<<(COUT * CIN) / 256, 256, 0, stream>>>(w, wAf, wsq);
  modulate_kernel<<<NB * 32, 256, 0, stream>>>(x, s, xpad);
  calc_rsig_kernel<<<(NB * COUT) / 4, 256, 0, stream>>>(s, wsq, rsig);
  conv_gemm_kernel<<<dim3(NPIX / 256, COUT / 128, 2), 256, 0, stream>>>(
      wAf, xpad, rsig, out, two_partials ? p0 : nullptr, p1);
  const int mblocks = (NPIX * COUT / 8) / 256;   // 4096
  if (two_partials)
    merge2_kernel<<<mblocks, 256, 0, stream>>>(out, p0, p1);
  else
    merge1_kernel<<<mblocks, 256, 0, stream>>>(out, p1);
}

// Round 13
// 149.254 us; speedup vs baseline: 1.1265x; 1.1265x over previous
//
#include <hip/hip_runtime.h>
#include <hip/hip_bf16.h>

// Modulated conv2d (StyleGAN2) on MI355X.
// out[b,o] = rsig[b,o] * conv(s[b,:]*x[b,:], W*SCALE)   (shared weights)
// rsig[b,o] = 1/sqrt(sum_i s[b,i]^2 * wsq[o,i] + 1e-8)
// Conv as implicit GEMM: D[o][p] = sum_k Wb[o][k] * Xcl[p][k].
//
// R13 = R6's proven conv body (256 thr, 4 waves 2Mx2N, per-wave 64x128,
// single-buffer 48KB LDS, 2x __syncthreads per K-tile) with z-split x3:
// grid 64x4x3 = 768 blocks = 3 INDEPENDENT blocks/CU. Mechanism (R8 vs R6
// isolates it): independent co-resident blocks cover each other's
// barrier/vmcnt-drain stalls; 2 blocks -> 46% MfmaUtil, 3 should raise it.
// Per-CU MFMA/LDS-read/write totals invariant vs R6. Tail: 3 bf16 partials
// + merge3; halo-only zero (R9/R10-verified). Fallbacks if ws is small:
// nz=2 + merge2; last resort f32-direct z0 + merge1 (R6 scheme).

typedef __attribute__((ext_vector_type(4))) float f32x4;
typedef __attribute__((ext_vector_type(8))) short bf16x8;

#define NB    16
#define CIN   512
#define COUT  512
#define KTOT  4608           // CIN * 9
#define NPIX  (NB * 32 * 32) // 16384

__device__ __forceinline__ void gload_lds16(const void* g, void* l) {
  __builtin_amdgcn_global_load_lds(
      (__attribute__((address_space(1))) void*)(g),
      (__attribute__((address_space(3))) void*)(l), 16, 0, 0);
}

__device__ __forceinline__ float bf16bits_to_f32(short v) {
  return __uint_as_float(((unsigned)(unsigned short)v) << 16);
}

// ---- kernel 1: pack weights (bf16, [o][tap*512+ci]) + wsq ----
__global__ __launch_bounds__(256) void pack_w_kernel(
    const float* __restrict__ w, __hip_bfloat16* __restrict__ wB,
    float* __restrict__ wsq) {
  const int idx = blockIdx.x * 256 + threadIdx.x;   // = o*512 + ci
  const int o = idx >> 9, ci = idx & 511;
  const float* wp = w + (size_t)idx * 9;
  const float WSCALE = 0.014731391274719739f;       // 1/sqrt(512*9)
  float sum = 0.f;
#pragma unroll
  for (int t = 0; t < 9; ++t) {
    float v = wp[t] * WSCALE;
    sum += v * v;
    wB[(size_t)o * KTOT + t * 512 + ci] = __float2bfloat16(v);
  }
  wsq[idx] = sum;
}

// ---- kernel 2: rsig[b][o], one wave per (b,o) ----
__global__ __launch_bounds__(256) void calc_rsig_kernel(
    const float* __restrict__ s, const float* __restrict__ wsq,
    float* __restrict__ rsig) {
  const int wid = blockIdx.x * 4 + (threadIdx.x >> 6); // b*512 + o
  const int lane = threadIdx.x & 63;
  const int b = wid >> 9, o = wid & 511;
  const float* sp = s + b * 512;
  const float* wp = wsq + o * 512;
  float sum = 0.f;
#pragma unroll
  for (int i = 0; i < 8; ++i) {
    float sv = sp[lane + i * 64];
    sum += sv * sv * wp[lane + i * 64];
  }
#pragma unroll
  for (int off = 32; off > 0; off >>= 1) sum += __shfl_down(sum, off, 64);
  if (lane == 0) rsig[wid] = 1.0f / sqrtf(sum + 1e-8f);
}

// ---- kernel 3: modulate + NCHW -> padded channels-last bf16 ----
__global__ __launch_bounds__(256) void modulate_kernel(
    const float* __restrict__ x, const float* __restrict__ s,
    __hip_bfloat16* __restrict__ xpad) {
  const int by = blockIdx.x;            // b*32 + y
  const int b = by >> 5, y = by & 31;
  __shared__ __attribute__((aligned(16))) __hip_bfloat16 tile[32][72];
  const int tid = threadIdx.x;
  const int xc = tid & 31;
  const int cr0 = tid >> 5;
  const float* xrow = x + ((size_t)b * 512 * 32 + y) * 32;
  const float* sb = s + b * 512;
  __hip_bfloat16* orow = xpad + (size_t)((b * 34 + y + 1) * 34) * 512;

  for (int ci0 = 0; ci0 < 512; ci0 += 64) {
#pragma unroll
    for (int r = 0; r < 8; ++r) {
      const int cir = r * 8 + cr0;
      const int ci = ci0 + cir;
      float v = xrow[(size_t)ci * 1024 + xc] * sb[ci];
      tile[xc][cir] = __float2bfloat16(v);
    }
    __syncthreads();
    const int xcw = tid >> 3, vec = tid & 7;
    bf16x8 v = *(const bf16x8*)&tile[xcw][vec * 8];
    *(bf16x8*)(orow + (size_t)(xcw + 1) * 512 + ci0 + vec * 8) = v;
    __syncthreads();
  }
}

// ---- kernel 3b: zero only the halo of xpad ----
__global__ __launch_bounds__(256) void halo_zero_kernel(
    __hip_bfloat16* __restrict__ xpad) {
  const int sb = blockIdx.x;           // b*132 + site
  const int b = sb / 132, s = sb - b * 132;
  int y, x;
  if (s < 34)       { y = 0;        x = s; }
  else if (s < 68)  { y = 33;       x = s - 34; }
  else if (s < 100) { y = s - 67;   x = 0; }
  else              { y = s - 99;   x = 33; }
  unsigned* p = (unsigned*)(xpad + (size_t)((b * 34 + y) * 34 + x) * 512);
  p[threadIdx.x] = 0u;   // 256 x 4B = 512 bf16
}

// ---- kernel 4: implicit-GEMM conv, R6 body, nz-way z-split ----
// Block: 128 cout x 256 pix x K(4608/nz). 4 waves 2Mx2N, per-wave 64x128.
// LDS: A[128][64] 16KB + B[256][64] 32KB, single-buffered, row-major 128B
// rows, XOR swizzle byte^=((row&7)<<4) on staging source chunk + ds_read
// (rule 21; 0 conflicts R1-R12).
__global__ __launch_bounds__(256, 3) void conv_gemm_kernel(
    const __hip_bfloat16* __restrict__ wB,    // [512][4608]
    const __hip_bfloat16* __restrict__ xpad,  // [16][34][34][512]
    const float* __restrict__ rsig,           // [16][512]
    float* __restrict__ out,                  // f32 out (last-resort, z=0)
    __hip_bfloat16* __restrict__ p0,          // bf16 partial z=0 (or null)
    __hip_bfloat16* __restrict__ p1,          // bf16 partial z=1
    __hip_bfloat16* __restrict__ p2,          // bf16 partial z=2 (nz=3)
    int ktpz) {                               // K64-tiles per z (72/nz)
  __shared__ __attribute__((aligned(16))) __hip_bfloat16 ldsA[128 * 64];
  __shared__ __attribute__((aligned(16))) __hip_bfloat16 ldsB[256 * 64];

  const int tid = threadIdx.x;
  const int wv = tid >> 6, lane = tid & 63, l15 = lane & 15;
  const int bo0 = blockIdx.y << 7;   // cout block (128)
  const int bp0 = blockIdx.x << 8;   // pixel block (256; 256 | 1024 per image)
  const int z = blockIdx.z;
  const int zbase = z * ktpz;
  const int bimg = blockIdx.x >> 2;
  const int wr = wv >> 1, wc = wv & 1;

  // Staging source offsets (pre-swizzled chunk within row; rule 21).
  int gA[4];   // + ktg*64 per tile
#pragma unroll
  for (int r = 0; r < 4; ++r) {
    const int c = r * 256 + tid, row = c >> 3, sc = (c & 7) ^ (row & 7);
    gA[r] = (bo0 + row) * KTOT + sc * 8;
  }
  int gB[8];   // + tapoff*512 + ci0 per tile
#pragma unroll
  for (int r = 0; r < 8; ++r) {
    const int c = r * 256 + tid, row = c >> 3, sc = (c & 7) ^ (row & 7);
    const int p = bp0 + row, b = p >> 10, rem = p & 1023, y = rem >> 5,
              xx = rem & 31;
    gB[r] = ((b * 34 + y) * 34 + xx) * 512 + sc * 8;
  }

  f32x4 acc[4][8];
#pragma unroll
  for (int mi = 0; mi < 4; ++mi)
#pragma unroll
    for (int ni = 0; ni < 8; ++ni) acc[mi][ni] = f32x4{0.f, 0.f, 0.f, 0.f};

  const int kb0 = (lane >> 4) << 4;   // byte base of this lane's k-slot

#pragma unroll 1
  for (int kt = 0; kt < ktpz; ++kt) {
    const int ktg = zbase + kt;
    const int tap = ktg >> 3;
    const int xoff = (tap + 31 * (tap / 3)) * 512 + ((ktg & 7) << 6);
    // ---- stage tile (12 x 16B per thread) ----
#pragma unroll
    for (int r = 0; r < 4; ++r)
      gload_lds16(wB + (size_t)(gA[r] + (ktg << 6)),
                  (char*)ldsA + (r * 256 + tid) * 16);
#pragma unroll
    for (int r = 0; r < 8; ++r)
      gload_lds16(xpad + (size_t)(gB[r] + xoff),
                  (char*)ldsB + (r * 256 + tid) * 16);
    __syncthreads();   // drains vmcnt -> staged data visible

    bf16x8 af[4][2];
#pragma unroll
    for (int mi = 0; mi < 4; ++mi) {
      const int row = (wr << 6) + (mi << 4) + l15;
      const int swz = (row & 7) << 4;
      af[mi][0] = *(const bf16x8*)((const char*)ldsA + row * 128 + (kb0 ^ swz));
      af[mi][1] = *(const bf16x8*)((const char*)ldsA + row * 128 + ((64 | kb0) ^ swz));
    }
    {
      bf16x8 bv[8];
#pragma unroll
      for (int ni = 0; ni < 8; ++ni) {
        const int row = (wc << 7) + (ni << 4) + l15;
        bv[ni] = *(const bf16x8*)((const char*)ldsB + row * 128 +
                                  (kb0 ^ ((row & 7) << 4)));
      }
#pragma unroll
      for (int mi = 0; mi < 4; ++mi)
#pragma unroll
        for (int ni = 0; ni < 8; ++ni)
          acc[mi][ni] = __builtin_amdgcn_mfma_f32_16x16x32_bf16(
              af[mi][0], bv[ni], acc[mi][ni], 0, 0, 0);
    }
    {
      bf16x8 bv[8];
#pragma unroll
      for (int ni = 0; ni < 8; ++ni) {
        const int row = (wc << 7) + (ni << 4) + l15;
        bv[ni] = *(const bf16x8*)((const char*)ldsB + row * 128 +
                                  ((64 | kb0) ^ ((row & 7) << 4)));
      }
#pragma unroll
      for (int mi = 0; mi < 4; ++mi)
#pragma unroll
        for (int ni = 0; ni < 8; ++ni)
          acc[mi][ni] = __builtin_amdgcn_mfma_f32_16x16x32_bf16(
              af[mi][1], bv[ni], acc[mi][ni], 0, 0, 0);
    }
    __syncthreads();   // all reads done before next stage overwrites
  }

  // Epilogue: scale by rsig -> bf16 partial pz (f32 out if p0==null && z==0).
  // C/D: col(=p)=lane&15, row(=o)=(lane>>4)*4+r
  __hip_bfloat16* pz = (z == 0) ? p0 : ((z == 1) ? p1 : p2);
  const bool f32path = (p0 == nullptr) && (z == 0);
#pragma unroll
  for (int mi = 0; mi < 4; ++mi) {
    const int o = bo0 + (wr << 6) + (mi << 4) + ((lane >> 4) << 2);
    const f32x4 rs = *(const f32x4*)(rsig + (bimg << 9) + o);
#pragma unroll
    for (int ni = 0; ni < 8; ++ni) {
      const int p = bp0 + (wc << 7) + (ni << 4) + l15;
      const int prem = p & 1023;
#pragma unroll
      for (int r = 0; r < 4; ++r) {
        const float v = acc[mi][ni][r] * rs[r];
        const size_t oidx = ((size_t)((bimg << 9) + o + r)) * 1024 + prem;
        if (f32path) out[oidx] = v;
        else pz[oidx] = __float2bfloat16(v);
      }
    }
  }
}

// ---- kernel 5a: merge out = p0 + p1 + p2 ----
__global__ __launch_bounds__(256) void merge3_kernel(
    float* __restrict__ out, const __hip_bfloat16* __restrict__ p0,
    const __hip_bfloat16* __restrict__ p1,
    const __hip_bfloat16* __restrict__ p2) {
  const size_t i = (size_t)blockIdx.x * 256 + threadIdx.x;
  const bf16x8 a = ((const bf16x8*)p0)[i];
  const bf16x8 b = ((const bf16x8*)p1)[i];
  const bf16x8 c = ((const bf16x8*)p2)[i];
  f32x4 o0, o1;
#pragma unroll
  for (int j = 0; j < 4; ++j) {
    o0[j] = bf16bits_to_f32(a[j]) + bf16bits_to_f32(b[j]) +
            bf16bits_to_f32(c[j]);
    o1[j] = bf16bits_to_f32(a[4 + j]) + bf16bits_to_f32(b[4 + j]) +
            bf16bits_to_f32(c[4 + j]);
  }
  ((f32x4*)out)[2 * i] = o0;
  ((f32x4*)out)[2 * i + 1] = o1;
}

// ---- kernel 5b: merge out = p0 + p1 ----
__global__ __launch_bounds__(256) void merge2_kernel(
    float* __restrict__ out, const __hip_bfloat16* __restrict__ p0,
    const __hip_bfloat16* __restrict__ p1) {
  const size_t i = (size_t)blockIdx.x * 256 + threadIdx.x;
  const bf16x8 a = ((const bf16x8*)p0)[i];
  const bf16x8 b = ((const bf16x8*)p1)[i];
  f32x4 o0, o1;
#pragma unroll
  for (int j = 0; j < 4; ++j) {
    o0[j] = bf16bits_to_f32(a[j]) + bf16bits_to_f32(b[j]);
    o1[j] = bf16bits_to_f32(a[4 + j]) + bf16bits_to_f32(b[4 + j]);
  }
  ((f32x4*)out)[2 * i] = o0;
  ((f32x4*)out)[2 * i + 1] = o1;
}

// ---- kernel 5c: last-resort merge out += p1 ----
__global__ __launch_bounds__(256) void merge1_kernel(
    float* __restrict__ out, const __hip_bfloat16* __restrict__ p1) {
  const size_t i = (size_t)blockIdx.x * 256 + threadIdx.x;
  f32x4* o4 = (f32x4*)out + 2 * i;
  f32x4 a = o4[0], b = o4[1];
  const bf16x8 pv = ((const bf16x8*)p1)[i];
#pragma unroll
  for (int j = 0; j < 4; ++j) {
    a[j] += bf16bits_to_f32(pv[j]);
    b[j] += bf16bits_to_f32(pv[4 + j]);
  }
  o4[0] = a;
  o4[1] = b;
}

extern "C" void kernel_launch(void* const* d_in, const int* in_sizes, int n_in,
                              void* d_out, int out_size, void* d_ws,
                              size_t ws_size, hipStream_t stream) {
  const float* x = (const float*)d_in[0];   // [16,512,32,32]
  const float* s = (const float*)d_in[1];   // [16,512]
  const float* w = (const float*)d_in[2];   // [512,512,3,3]
  float* out = (float*)d_out;               // [16,512,32,32] f32

  char* ws = (char*)d_ws;
  const size_t xpad_bytes = (size_t)NB * 34 * 34 * 512 * 2;  // 18,939,904
  const size_t wB_bytes = (size_t)COUT * KTOT * 2;           //  4,718,592
  const size_t wsq_bytes = (size_t)COUT * CIN * 4;           //  1,048,576
  const size_t rsig_bytes = (size_t)NB * COUT * 4;           //     32,768
  const size_t part_bytes = (size_t)NPIX * COUT * 2;         // 16,777,216
  const size_t base_bytes = xpad_bytes + wB_bytes + wsq_bytes + rsig_bytes;
  __hip_bfloat16* xpad = (__hip_bfloat16*)ws;
  __hip_bfloat16* wB = (__hip_bfloat16*)(ws + xpad_bytes);
  float* wsq = (float*)(ws + xpad_bytes + wB_bytes);
  float* rsig = (float*)(ws + xpad_bytes + wB_bytes + wsq_bytes);
  __hip_bfloat16* pa = (__hip_bfloat16*)(ws + base_bytes);
  __hip_bfloat16* pb = (__hip_bfloat16*)(ws + base_bytes + part_bytes);
  __hip_bfloat16* pc = (__hip_bfloat16*)(ws + base_bytes + 2 * part_bytes);
  const bool fits3 = ws_size >= base_bytes + 3 * part_bytes;
  const bool fits2 = ws_size >= base_bytes + 2 * part_bytes;

  halo_zero_kernel<<<NB * 132, 256, 0, stream>>>(xpad);
  pack_w_kernel<<<(COUT * CIN) / 256, 256, 0, stream>>>(w, wB, wsq);
  modulate_kernel<<<NB * 32, 256, 0, stream>>>(x, s, xpad);
  calc_rsig_kernel<<<(NB * COUT) / 4, 256, 0, stream>>>(s, wsq, rsig);

  const int mblocks = (NPIX * COUT / 8) / 256;   // 4096
  if (fits3) {
    conv_gemm_kernel<<<dim3(NPIX / 256, COUT / 128, 3), 256, 0, stream>>>(
        wB, xpad, rsig, out, pa, pb, pc, 24);
    merge3_kernel<<<mblocks, 256, 0, stream>>>(out, pa, pb, pc);
  } else if (fits2) {
    conv_gemm_kernel<<<dim3(NPIX / 256, COUT / 128, 2), 256, 0, stream>>>(
        wB, xpad, rsig, out, pa, pb, nullptr, 36);
    merge2_kernel<<<mblocks, 256, 0, stream>>>(out, pa, pb);
  } else {
    conv_gemm_kernel<<<dim3(NPIX / 256, COUT / 128, 2), 256, 0, stream>>>(
        wB, xpad, rsig, out, nullptr, pa, nullptr, 36);
    merge1_kernel<<<mblocks, 256, 0, stream>>>(out, pa);
  }
}

// Round 14
// 116.115 us; speedup vs baseline: 1.4480x; 1.2854x over previous
//
#include <hip/hip_runtime.h>
#include <hip/hip_bf16.h>

// Modulated conv2d (StyleGAN2) on MI355X.
// out[b,o] = rsig[b,o] * conv(s[b,:]*x[b,:], W*SCALE)   (shared weights)
// rsig[b,o] = 1/sqrt(sum_i s[b,i]^2 * wsq[o,i] + 1e-8)
// Conv as implicit GEMM: D[o][p] = sum_k Wb[o][k] * Xcl[p][k].
//
// R14 = R6 geometry (128x256 tile, 4 waves 2Mx2N, per-wave 64x128, z-split
// x2 -> 512 blocks = 2 INDEPENDENT blocks/CU) + the never-combined second
// mechanism: counted-vmcnt double-buffered pipeline.
//  - BK=32: LDS buf = A[128][32] 8KB + B[256][32] 16KB; dbuf 48KB/block ->
//    2 blocks = 96KB <= 160KB (this is what BK=64 dbuf couldn't do).
//  - 64B rows are BANK-CONFLICT-FREE UNSWIZZLED for the 16-row x 4-quadrant
//    fragment read (per-bank load = exactly 8 req/wave = data floor) ->
//    linear LDS, trivial linear staging.
//  - Per K32-tile: {vmcnt(6) -> BAR -> 12 ds_read_b128 + 32 MFMA -> BAR ->
//    stage(kt+2, same parity)}. Stage->use distance ~2 tiles (~1600cyc >
//    900cyc HBM latency); vmcnt never drains to 0 in steady state.
// Tail = R10 verified: halo-zero, bf16 partials both z, merge2 (+fallback).

typedef __attribute__((ext_vector_type(4))) float f32x4;
typedef __attribute__((ext_vector_type(8))) short bf16x8;

#define NB    16
#define CIN   512
#define COUT  512
#define KTOT  4608           // CIN * 9
#define NPIX  (NB * 32 * 32) // 16384
#define KT32  72             // K32-tiles per z-half

#define WAITV6() asm volatile("s_waitcnt vmcnt(6)" ::: "memory")
#define WAITV0() asm volatile("s_waitcnt vmcnt(0)" ::: "memory")
#define FENCE()  asm volatile("" ::: "memory")
#define BAR()    { FENCE(); __builtin_amdgcn_s_barrier(); FENCE(); }

__device__ __forceinline__ void gload_lds16(const void* g, void* l) {
  __builtin_amdgcn_global_load_lds(
      (__attribute__((address_space(1))) void*)(g),
      (__attribute__((address_space(3))) void*)(l), 16, 0, 0);
}

__device__ __forceinline__ float bf16bits_to_f32(short v) {
  return __uint_as_float(((unsigned)(unsigned short)v) << 16);
}

// ---- kernel 1: pack weights (bf16, [o][tap*512+ci]) + wsq ----
__global__ __launch_bounds__(256) void pack_w_kernel(
    const float* __restrict__ w, __hip_bfloat16* __restrict__ wB,
    float* __restrict__ wsq) {
  const int idx = blockIdx.x * 256 + threadIdx.x;   // = o*512 + ci
  const int o = idx >> 9, ci = idx & 511;
  const float* wp = w + (size_t)idx * 9;
  const float WSCALE = 0.014731391274719739f;       // 1/sqrt(512*9)
  float sum = 0.f;
#pragma unroll
  for (int t = 0; t < 9; ++t) {
    float v = wp[t] * WSCALE;
    sum += v * v;
    wB[(size_t)o * KTOT + t * 512 + ci] = __float2bfloat16(v);
  }
  wsq[idx] = sum;
}

// ---- kernel 2: rsig[b][o], one wave per (b,o) ----
__global__ __launch_bounds__(256) void calc_rsig_kernel(
    const float* __restrict__ s, const float* __restrict__ wsq,
    float* __restrict__ rsig) {
  const int wid = blockIdx.x * 4 + (threadIdx.x >> 6); // b*512 + o
  const int lane = threadIdx.x & 63;
  const int b = wid >> 9, o = wid & 511;
  const float* sp = s + b * 512;
  const float* wp = wsq + o * 512;
  float sum = 0.f;
#pragma unroll
  for (int i = 0; i < 8; ++i) {
    float sv = sp[lane + i * 64];
    sum += sv * sv * wp[lane + i * 64];
  }
#pragma unroll
  for (int off = 32; off > 0; off >>= 1) sum += __shfl_down(sum, off, 64);
  if (lane == 0) rsig[wid] = 1.0f / sqrtf(sum + 1e-8f);
}

// ---- kernel 3: modulate + NCHW -> padded channels-last bf16 ----
__global__ __launch_bounds__(256) void modulate_kernel(
    const float* __restrict__ x, const float* __restrict__ s,
    __hip_bfloat16* __restrict__ xpad) {
  const int by = blockIdx.x;            // b*32 + y
  const int b = by >> 5, y = by & 31;
  __shared__ __attribute__((aligned(16))) __hip_bfloat16 tile[32][72];
  const int tid = threadIdx.x;
  const int xc = tid & 31;
  const int cr0 = tid >> 5;
  const float* xrow = x + ((size_t)b * 512 * 32 + y) * 32;
  const float* sb = s + b * 512;
  __hip_bfloat16* orow = xpad + (size_t)((b * 34 + y + 1) * 34) * 512;

  for (int ci0 = 0; ci0 < 512; ci0 += 64) {
#pragma unroll
    for (int r = 0; r < 8; ++r) {
      const int cir = r * 8 + cr0;
      const int ci = ci0 + cir;
      float v = xrow[(size_t)ci * 1024 + xc] * sb[ci];
      tile[xc][cir] = __float2bfloat16(v);
    }
    __syncthreads();
    const int xcw = tid >> 3, vec = tid & 7;
    bf16x8 v = *(const bf16x8*)&tile[xcw][vec * 8];
    *(bf16x8*)(orow + (size_t)(xcw + 1) * 512 + ci0 + vec * 8) = v;
    __syncthreads();
  }
}

// ---- kernel 3b: zero only the halo of xpad ----
__global__ __launch_bounds__(256) void halo_zero_kernel(
    __hip_bfloat16* __restrict__ xpad) {
  const int sb = blockIdx.x;           // b*132 + site
  const int b = sb / 132, s = sb - b * 132;
  int y, x;
  if (s < 34)       { y = 0;        x = s; }
  else if (s < 68)  { y = 33;       x = s - 34; }
  else if (s < 100) { y = s - 67;   x = 0; }
  else              { y = s - 99;   x = 33; }
  unsigned* p = (unsigned*)(xpad + (size_t)((b * 34 + y) * 34 + x) * 512);
  p[threadIdx.x] = 0u;   // 256 x 4B = 512 bf16
}

// ---- kernel 4: implicit-GEMM conv, BK=32 dbuf counted-vmcnt, 2 blk/CU ----
// LDS (static 96KB/2blocks): A0[128][32] A1 at 8192; B0[256][32] at 16384,
// B1 at 32768. All linear (no swizzle needed at 64B rows; see header).
#define CONV_BODY(KT, PAR)                                                    \
  {                                                                           \
    const int kt_ = (KT);                                                     \
    if (kt_ < KT32 - 1) { WAITV6(); } else { WAITV0(); }                      \
    BAR();                                                                    \
    const char* bA = ldsc + (PAR)*8192;                                       \
    const char* bB = ldsc + 16384 + (PAR)*16384;                              \
    bf16x8 af[4], bv[8];                                                      \
    _Pragma("unroll")                                                         \
    for (int mi = 0; mi < 4; ++mi) {                                          \
      const int row = (wr << 6) + (mi << 4) + l15;                            \
      af[mi] = *(const bf16x8*)(bA + row * 64 + kb0);                         \
    }                                                                         \
    _Pragma("unroll")                                                         \
    for (int ni = 0; ni < 8; ++ni) {                                          \
      const int row = (wc << 7) + (ni << 4) + l15;                            \
      bv[ni] = *(const bf16x8*)(bB + row * 64 + kb0);                         \
    }                                                                         \
    _Pragma("unroll")                                                         \
    for (int mi = 0; mi < 4; ++mi)                                            \
      _Pragma("unroll")                                                       \
      for (int ni = 0; ni < 8; ++ni)                                          \
        acc[mi][ni] = __builtin_amdgcn_mfma_f32_16x16x32_bf16(                \
            af[mi], bv[ni], acc[mi][ni], 0, 0, 0);                            \
    BAR();                                                                    \
    if (kt_ + 2 < KT32) stage(kt_ + 2, (PAR));                                \
  }

__global__ __launch_bounds__(256, 2) void conv_gemm_kernel(
    const __hip_bfloat16* __restrict__ wB,    // [512][4608]
    const __hip_bfloat16* __restrict__ xpad,  // [16][34][34][512]
    const float* __restrict__ rsig,           // [16][512]
    float* __restrict__ out,                  // f32 out (fallback, z=0)
    __hip_bfloat16* __restrict__ p0,          // bf16 partial z=0 (or null)
    __hip_bfloat16* __restrict__ p1) {        // bf16 partial z=1
  __shared__ __attribute__((aligned(16))) char ldsc[49152];

  const int tid = threadIdx.x;
  const int wv = tid >> 6, lane = tid & 63, l15 = lane & 15;
  const int bo0 = blockIdx.y << 7;   // cout block (128)
  const int bp0 = blockIdx.x << 8;   // pixel block (256; 256 | 1024 per image)
  const int z = blockIdx.z;          // K half: k32 tiles z*72 .. z*72+71
  const int zbase = z * KT32;
  const int bimg = blockIdx.x >> 2;
  const int wr = wv >> 1, wc = wv & 1;
  const int kb0 = (lane >> 4) << 4;  // 16B quadrant within 64B row

  // Staging source precompute (linear dest unit u -> (row, chunk)).
  int gA[2];   // + tap*512 + ci0 per tile (elements)
#pragma unroll
  for (int r = 0; r < 2; ++r) {
    const int u = r * 256 + tid, row = u >> 2, c = u & 3;
    gA[r] = (bo0 + row) * KTOT + c * 8;
  }
  int gB[4];   // + xoff per tile
#pragma unroll
  for (int r = 0; r < 4; ++r) {
    const int u = r * 256 + tid, row = u >> 2, c = u & 3;
    const int p = bp0 + row, b = p >> 10, rem = p & 1023, y = rem >> 5,
              xx = rem & 31;
    gB[r] = ((b * 34 + y) * 34 + xx) * 512 + c * 8;
  }

  auto stage = [&](int kt, int par) {   // 6 x 16B per thread
    const int k32g = zbase + kt;
    const int tap = k32g >> 4;                 // k32g/16 (512/32=16)
    const int ci0 = (k32g & 15) << 5;
    const int xoff = (tap + 31 * (tap / 3)) * 512 + ci0;
    char* dA = ldsc + par * 8192;
    char* dB = ldsc + 16384 + par * 16384;
#pragma unroll
    for (int r = 0; r < 2; ++r)
      gload_lds16(wB + (size_t)(gA[r] + tap * 512 + ci0),
                  dA + (r * 256 + tid) * 16);
#pragma unroll
    for (int r = 0; r < 4; ++r)
      gload_lds16(xpad + (size_t)(gB[r] + xoff), dB + (r * 256 + tid) * 16);
  };

  f32x4 acc[4][8];
#pragma unroll
  for (int mi = 0; mi < 4; ++mi)
#pragma unroll
    for (int ni = 0; ni < 8; ++ni) acc[mi][ni] = f32x4{0.f, 0.f, 0.f, 0.f};

  // Prologue: stage tiles 0 (par 0) and 1 (par 1) -> 12 outstanding.
  stage(0, 0);
  stage(1, 1);

#pragma unroll 1
  for (int kt = 0; kt < KT32; kt += 2) {
    CONV_BODY(kt, 0);
    CONV_BODY(kt + 1, 1);
  }

  // Epilogue: scale by rsig -> bf16 partial pz (f32 out if p0==null && z==0).
  // C/D: col(=p)=lane&15, row(=o)=(lane>>4)*4+r
  __hip_bfloat16* pz = z ? p1 : p0;
  const bool f32path = (p0 == nullptr) && (z == 0);
#pragma unroll
  for (int mi = 0; mi < 4; ++mi) {
    const int o = bo0 + (wr << 6) + (mi << 4) + ((lane >> 4) << 2);
    const f32x4 rs = *(const f32x4*)(rsig + (bimg << 9) + o);
#pragma unroll
    for (int ni = 0; ni < 8; ++ni) {
      const int p = bp0 + (wc << 7) + (ni << 4) + l15;
      const int prem = p & 1023;
#pragma unroll
      for (int r = 0; r < 4; ++r) {
        const float v = acc[mi][ni][r] * rs[r];
        const size_t oidx = ((size_t)((bimg << 9) + o + r)) * 1024 + prem;
        if (f32path) out[oidx] = v;
        else pz[oidx] = __float2bfloat16(v);
      }
    }
  }
}

// ---- kernel 5a: merge out = p0 + p1 ----
__global__ __launch_bounds__(256) void merge2_kernel(
    float* __restrict__ out, const __hip_bfloat16* __restrict__ p0,
    const __hip_bfloat16* __restrict__ p1) {
  const size_t i = (size_t)blockIdx.x * 256 + threadIdx.x;
  const bf16x8 a = ((const bf16x8*)p0)[i];
  const bf16x8 b = ((const bf16x8*)p1)[i];
  f32x4 o0, o1;
#pragma unroll
  for (int j = 0; j < 4; ++j) {
    o0[j] = bf16bits_to_f32(a[j]) + bf16bits_to_f32(b[j]);
    o1[j] = bf16bits_to_f32(a[4 + j]) + bf16bits_to_f32(b[4 + j]);
  }
  ((f32x4*)out)[2 * i] = o0;
  ((f32x4*)out)[2 * i + 1] = o1;
}

// ---- kernel 5b: fallback merge out += p1 ----
__global__ __launch_bounds__(256) void merge1_kernel(
    float* __restrict__ out, const __hip_bfloat16* __restrict__ p1) {
  const size_t i = (size_t)blockIdx.x * 256 + threadIdx.x;
  f32x4* o4 = (f32x4*)out + 2 * i;
  f32x4 a = o4[0], b = o4[1];
  const bf16x8 pv = ((const bf16x8*)p1)[i];
#pragma unroll
  for (int j = 0; j < 4; ++j) {
    a[j] += bf16bits_to_f32(pv[j]);
    b[j] += bf16bits_to_f32(pv[4 + j]);
  }
  o4[0] = a;
  o4[1] = b;
}

extern "C" void kernel_launch(void* const* d_in, const int* in_sizes, int n_in,
                              void* d_out, int out_size, void* d_ws,
                              size_t ws_size, hipStream_t stream) {
  const float* x = (const float*)d_in[0];   // [16,512,32,32]
  const float* s = (const float*)d_in[1];   // [16,512]
  const float* w = (const float*)d_in[2];   // [512,512,3,3]
  float* out = (float*)d_out;               // [16,512,32,32] f32

  char* ws = (char*)d_ws;
  const size_t xpad_bytes = (size_t)NB * 34 * 34 * 512 * 2;  // 18,939,904
  const size_t wB_bytes = (size_t)COUT * KTOT * 2;           //  4,718,592
  const size_t wsq_bytes = (size_t)COUT * CIN * 4;           //  1,048,576
  const size_t rsig_bytes = (size_t)NB * COUT * 4;           //     32,768
  const size_t part_bytes = (size_t)NPIX * COUT * 2;         // 16,777,216
  const size_t base_bytes = xpad_bytes + wB_bytes + wsq_bytes + rsig_bytes;
  __hip_bfloat16* xpad = (__hip_bfloat16*)ws;
  __hip_bfloat16* wB = (__hip_bfloat16*)(ws + xpad_bytes);
  float* wsq = (float*)(ws + xpad_bytes + wB_bytes);
  float* rsig = (float*)(ws + xpad_bytes + wB_bytes + wsq_bytes);
  __hip_bfloat16* pa = (__hip_bfloat16*)(ws + base_bytes);
  __hip_bfloat16* pb = (__hip_bfloat16*)(ws + base_bytes + part_bytes);
  const bool fits2 = ws_size >= base_bytes + 2 * part_bytes;

  halo_zero_kernel<<<NB * 132, 256, 0, stream>>>(xpad);
  pack_w_kernel<<<(COUT * CIN) / 256, 256, 0, stream>>>(w, wB, wsq);
  modulate_kernel<<<NB * 32, 256, 0, stream>>>(x, s, xpad);
  calc_rsig_kernel<<<(NB * COUT) / 4, 256, 0, stream>>>(s, wsq, rsig);

  const int mblocks = (NPIX * COUT / 8) / 256;   // 4096
  if (fits2) {
    conv_gemm_kernel<<<dim3(NPIX / 256, COUT / 128, 2), 256, 0, stream>>>(
        wB, xpad, rsig, out, pa, pb);
    merge2_kernel<<<mblocks, 256, 0, stream>>>(out, pa, pb);
  } else {
    conv_gemm_kernel<<<dim3(NPIX / 256, COUT / 128, 2), 256, 0, stream>>>(
        wB, xpad, rsig, out, nullptr, pa);
    merge1_kernel<<<mblocks, 256, 0, stream>>>(out, pa);
  }
}

// Round 15
// 115.892 us; speedup vs baseline: 1.4508x; 1.0019x over previous
//
#include <hip/hip_runtime.h>
#include <hip/hip_bf16.h>

// Modulated conv2d (StyleGAN2) on MI355X.
// out[b,o] = rsig[b,o] * conv(s[b,:]*x[b,:], W*SCALE)   (shared weights)
// rsig[b,o] = 1/sqrt(sum_i s[b,i]^2 * wsq[o,i] + 1e-8)
// Conv as implicit GEMM: D[o][p] = sum_k Wb[o][k] * Xcl[p][k].
//
// R15 = R14 (BK=32 double-buffered counted-vmcnt pipeline, 2 independent
// blocks/CU, z-split x2) + the bank-conflict fix R14 was missing:
//   R14's 64B rows put a quarter-wave (16 consecutive rows, one k-quadrant)
//   on only 2 of 8 bank-groups -> 8-way conflict (7.08M measured). Fix:
//   2-bit chunk swizzle c' = c ^ ((row>>1)&3) on the staging SOURCE chunk
//   and the read address (rule 21 involution). Bank group = (row&1,
//   q^((row>>1)&3)): 16 rows -> 8 groups x 2 lanes = conflict-free (m136).
//   Coalescing unchanged (permutation within each 64B source window).
// Pipeline: per K32-tile {vmcnt(6) -> BAR -> 12 ds_read_b128 + 32 MFMA ->
// BAR -> stage(kt+2, same parity)}; never drains in steady state.
// Tail = R10 verified: halo-zero, bf16 partials both z, merge2 (+fallback).

typedef __attribute__((ext_vector_type(4))) float f32x4;
typedef __attribute__((ext_vector_type(8))) short bf16x8;

#define NB    16
#define CIN   512
#define COUT  512
#define KTOT  4608           // CIN * 9
#define NPIX  (NB * 32 * 32) // 16384
#define KT32  72             // K32-tiles per z-half

#define WAITV6() asm volatile("s_waitcnt vmcnt(6)" ::: "memory")
#define WAITV0() asm volatile("s_waitcnt vmcnt(0)" ::: "memory")
#define FENCE()  asm volatile("" ::: "memory")
#define BAR()    { FENCE(); __builtin_amdgcn_s_barrier(); FENCE(); }

__device__ __forceinline__ void gload_lds16(const void* g, void* l) {
  __builtin_amdgcn_global_load_lds(
      (__attribute__((address_space(1))) void*)(g),
      (__attribute__((address_space(3))) void*)(l), 16, 0, 0);
}

__device__ __forceinline__ float bf16bits_to_f32(short v) {
  return __uint_as_float(((unsigned)(unsigned short)v) << 16);
}

// ---- kernel 1: pack weights (bf16, [o][tap*512+ci]) + wsq ----
__global__ __launch_bounds__(256) void pack_w_kernel(
    const float* __restrict__ w, __hip_bfloat16* __restrict__ wB,
    float* __restrict__ wsq) {
  const int idx = blockIdx.x * 256 + threadIdx.x;   // = o*512 + ci
  const int o = idx >> 9, ci = idx & 511;
  const float* wp = w + (size_t)idx * 9;
  const float WSCALE = 0.014731391274719739f;       // 1/sqrt(512*9)
  float sum = 0.f;
#pragma unroll
  for (int t = 0; t < 9; ++t) {
    float v = wp[t] * WSCALE;
    sum += v * v;
    wB[(size_t)o * KTOT + t * 512 + ci] = __float2bfloat16(v);
  }
  wsq[idx] = sum;
}

// ---- kernel 2: rsig[b][o], one wave per (b,o) ----
__global__ __launch_bounds__(256) void calc_rsig_kernel(
    const float* __restrict__ s, const float* __restrict__ wsq,
    float* __restrict__ rsig) {
  const int wid = blockIdx.x * 4 + (threadIdx.x >> 6); // b*512 + o
  const int lane = threadIdx.x & 63;
  const int b = wid >> 9, o = wid & 511;
  const float* sp = s + b * 512;
  const float* wp = wsq + o * 512;
  float sum = 0.f;
#pragma unroll
  for (int i = 0; i < 8; ++i) {
    float sv = sp[lane + i * 64];
    sum += sv * sv * wp[lane + i * 64];
  }
#pragma unroll
  for (int off = 32; off > 0; off >>= 1) sum += __shfl_down(sum, off, 64);
  if (lane == 0) rsig[wid] = 1.0f / sqrtf(sum + 1e-8f);
}

// ---- kernel 3: modulate + NCHW -> padded channels-last bf16 ----
__global__ __launch_bounds__(256) void modulate_kernel(
    const float* __restrict__ x, const float* __restrict__ s,
    __hip_bfloat16* __restrict__ xpad) {
  const int by = blockIdx.x;            // b*32 + y
  const int b = by >> 5, y = by & 31;
  __shared__ __attribute__((aligned(16))) __hip_bfloat16 tile[32][72];
  const int tid = threadIdx.x;
  const int xc = tid & 31;
  const int cr0 = tid >> 5;
  const float* xrow = x + ((size_t)b * 512 * 32 + y) * 32;
  const float* sb = s + b * 512;
  __hip_bfloat16* orow = xpad + (size_t)((b * 34 + y + 1) * 34) * 512;

  for (int ci0 = 0; ci0 < 512; ci0 += 64) {
#pragma unroll
    for (int r = 0; r < 8; ++r) {
      const int cir = r * 8 + cr0;
      const int ci = ci0 + cir;
      float v = xrow[(size_t)ci * 1024 + xc] * sb[ci];
      tile[xc][cir] = __float2bfloat16(v);
    }
    __syncthreads();
    const int xcw = tid >> 3, vec = tid & 7;
    bf16x8 v = *(const bf16x8*)&tile[xcw][vec * 8];
    *(bf16x8*)(orow + (size_t)(xcw + 1) * 512 + ci0 + vec * 8) = v;
    __syncthreads();
  }
}

// ---- kernel 3b: zero only the halo of xpad ----
__global__ __launch_bounds__(256) void halo_zero_kernel(
    __hip_bfloat16* __restrict__ xpad) {
  const int sb = blockIdx.x;           // b*132 + site
  const int b = sb / 132, s = sb - b * 132;
  int y, x;
  if (s < 34)       { y = 0;        x = s; }
  else if (s < 68)  { y = 33;       x = s - 34; }
  else if (s < 100) { y = s - 67;   x = 0; }
  else              { y = s - 99;   x = 33; }
  unsigned* p = (unsigned*)(xpad + (size_t)((b * 34 + y) * 34 + x) * 512);
  p[threadIdx.x] = 0u;   // 256 x 4B = 512 bf16
}

// ---- kernel 4: implicit-GEMM conv, BK=32 dbuf + chunk swizzle ----
// LDS (static 48KB/block, 2 blk/CU): A0[128][32] A1 at 8192; B0[256][32] at
// 16384, B1 at 32768. Slot swizzle c' = c ^ ((row>>1)&3) (see header).
#define CONV_BODY(KT, PAR)                                                    \
  {                                                                           \
    const int kt_ = (KT);                                                     \
    if (kt_ < KT32 - 1) { WAITV6(); } else { WAITV0(); }                      \
    BAR();                                                                    \
    const char* bA = ldsc + (PAR)*8192;                                       \
    const char* bB = ldsc + 16384 + (PAR)*16384;                              \
    bf16x8 af[4], bv[8];                                                      \
    _Pragma("unroll")                                                         \
    for (int mi = 0; mi < 4; ++mi) {                                          \
      const int row = (wr << 6) + (mi << 4) + l15;                            \
      const int slot = q4 ^ ((row >> 1) & 3);                                 \
      af[mi] = *(const bf16x8*)(bA + row * 64 + (slot << 4));                 \
    }                                                                         \
    _Pragma("unroll")                                                         \
    for (int ni = 0; ni < 8; ++ni) {                                          \
      const int row = (wc << 7) + (ni << 4) + l15;                            \
      const int slot = q4 ^ ((row >> 1) & 3);                                 \
      bv[ni] = *(const bf16x8*)(bB + row * 64 + (slot << 4));                 \
    }                                                                         \
    _Pragma("unroll")                                                         \
    for (int mi = 0; mi < 4; ++mi)                                            \
      _Pragma("unroll")                                                       \
      for (int ni = 0; ni < 8; ++ni)                                          \
        acc[mi][ni] = __builtin_amdgcn_mfma_f32_16x16x32_bf16(                \
            af[mi], bv[ni], acc[mi][ni], 0, 0, 0);                            \
    BAR();                                                                    \
    if (kt_ + 2 < KT32) stage(kt_ + 2, (PAR));                                \
  }

__global__ __launch_bounds__(256, 2) void conv_gemm_kernel(
    const __hip_bfloat16* __restrict__ wB,    // [512][4608]
    const __hip_bfloat16* __restrict__ xpad,  // [16][34][34][512]
    const float* __restrict__ rsig,           // [16][512]
    float* __restrict__ out,                  // f32 out (fallback, z=0)
    __hip_bfloat16* __restrict__ p0,          // bf16 partial z=0 (or null)
    __hip_bfloat16* __restrict__ p1) {        // bf16 partial z=1
  __shared__ __attribute__((aligned(16))) char ldsc[49152];

  const int tid = threadIdx.x;
  const int wv = tid >> 6, lane = tid & 63, l15 = lane & 15;
  const int q4 = lane >> 4;          // k-quadrant of this lane
  const int bo0 = blockIdx.y << 7;   // cout block (128)
  const int bp0 = blockIdx.x << 8;   // pixel block (256; 256 | 1024 per image)
  const int z = blockIdx.z;          // K half: k32 tiles z*72 .. z*72+71
  const int zbase = z * KT32;
  const int bimg = blockIdx.x >> 2;
  const int wr = wv >> 1, wc = wv & 1;

  // Staging source precompute: dest unit u -> row=u>>2, dest slot c=u&3,
  // source chunk sc = c ^ ((row>>1)&3)  (involution with the read swizzle).
  int gA[2];   // + tap*512 + ci0 per tile (elements)
#pragma unroll
  for (int r = 0; r < 2; ++r) {
    const int u = r * 256 + tid, row = u >> 2, c = u & 3;
    const int sc = c ^ ((row >> 1) & 3);
    gA[r] = (bo0 + row) * KTOT + sc * 8;
  }
  int gB[4];   // + xoff per tile
#pragma unroll
  for (int r = 0; r < 4; ++r) {
    const int u = r * 256 + tid, row = u >> 2, c = u & 3;
    const int sc = c ^ ((row >> 1) & 3);
    const int p = bp0 + row, b = p >> 10, rem = p & 1023, y = rem >> 5,
              xx = rem & 31;
    gB[r] = ((b * 34 + y) * 34 + xx) * 512 + sc * 8;
  }

  auto stage = [&](int kt, int par) {   // 6 x 16B per thread
    const int k32g = zbase + kt;
    const int tap = k32g >> 4;                 // 512/32 = 16 k32-steps per tap
    const int ci0 = (k32g & 15) << 5;
    const int xoff = (tap + 31 * (tap / 3)) * 512 + ci0;
    char* dA = ldsc + par * 8192;
    char* dB = ldsc + 16384 + par * 16384;
#pragma unroll
    for (int r = 0; r < 2; ++r)
      gload_lds16(wB + (size_t)(gA[r] + tap * 512 + ci0),
                  dA + (r * 256 + tid) * 16);
#pragma unroll
    for (int r = 0; r < 4; ++r)
      gload_lds16(xpad + (size_t)(gB[r] + xoff), dB + (r * 256 + tid) * 16);
  };

  f32x4 acc[4][8];
#pragma unroll
  for (int mi = 0; mi < 4; ++mi)
#pragma unroll
    for (int ni = 0; ni < 8; ++ni) acc[mi][ni] = f32x4{0.f, 0.f, 0.f, 0.f};

  // Prologue: stage tiles 0 (par 0) and 1 (par 1) -> 12 outstanding.
  stage(0, 0);
  stage(1, 1);

#pragma unroll 1
  for (int kt = 0; kt < KT32; kt += 2) {
    CONV_BODY(kt, 0);
    CONV_BODY(kt + 1, 1);
  }

  // Epilogue: scale by rsig -> bf16 partial pz (f32 out if p0==null && z==0).
  // C/D: col(=p)=lane&15, row(=o)=(lane>>4)*4+r
  __hip_bfloat16* pz = z ? p1 : p0;
  const bool f32path = (p0 == nullptr) && (z == 0);
#pragma unroll
  for (int mi = 0; mi < 4; ++mi) {
    const int o = bo0 + (wr << 6) + (mi << 4) + ((lane >> 4) << 2);
    const f32x4 rs = *(const f32x4*)(rsig + (bimg << 9) + o);
#pragma unroll
    for (int ni = 0; ni < 8; ++ni) {
      const int p = bp0 + (wc << 7) + (ni << 4) + l15;
      const int prem = p & 1023;
#pragma unroll
      for (int r = 0; r < 4; ++r) {
        const float v = acc[mi][ni][r] * rs[r];
        const size_t oidx = ((size_t)((bimg << 9) + o + r)) * 1024 + prem;
        if (f32path) out[oidx] = v;
        else pz[oidx] = __float2bfloat16(v);
      }
    }
  }
}

// ---- kernel 5a: merge out = p0 + p1 ----
__global__ __launch_bounds__(256) void merge2_kernel(
    float* __restrict__ out, const __hip_bfloat16* __restrict__ p0,
    const __hip_bfloat16* __restrict__ p1) {
  const size_t i = (size_t)blockIdx.x * 256 + threadIdx.x;
  const bf16x8 a = ((const bf16x8*)p0)[i];
  const bf16x8 b = ((const bf16x8*)p1)[i];
  f32x4 o0, o1;
#pragma unroll
  for (int j = 0; j < 4; ++j) {
    o0[j] = bf16bits_to_f32(a[j]) + bf16bits_to_f32(b[j]);
    o1[j] = bf16bits_to_f32(a[4 + j]) + bf16bits_to_f32(b[4 + j]);
  }
  ((f32x4*)out)[2 * i] = o0;
  ((f32x4*)out)[2 * i + 1] = o1;
}

// ---- kernel 5b: fallback merge out += p1 ----
__global__ __launch_bounds__(256) void merge1_kernel(
    float* __restrict__ out, const __hip_bfloat16* __restrict__ p1) {
  const size_t i = (size_t)blockIdx.x * 256 + threadIdx.x;
  f32x4* o4 = (f32x4*)out + 2 * i;
  f32x4 a = o4[0], b = o4[1];
  const bf16x8 pv = ((const bf16x8*)p1)[i];
#pragma unroll
  for (int j = 0; j < 4; ++j) {
    a[j] += bf16bits_to_f32(pv[j]);
    b[j] += bf16bits_to_f32(pv[4 + j]);
  }
  o4[0] = a;
  o4[1] = b;
}

extern "C" void kernel_launch(void* const* d_in, const int* in_sizes, int n_in,
                              void* d_out, int out_size, void* d_ws,
                              size_t ws_size, hipStream_t stream) {
  const float* x = (const float*)d_in[0];   // [16,512,32,32]
  const float* s = (const float*)d_in[1];   // [16,512]
  const float* w = (const float*)d_in[2];   // [512,512,3,3]
  float* out = (float*)d_out;               // [16,512,32,32] f32

  char* ws = (char*)d_ws;
  const size_t xpad_bytes = (size_t)NB * 34 * 34 * 512 * 2;  // 18,939,904
  const size_t wB_bytes = (size_t)COUT * KTOT * 2;           //  4,718,592
  const size_t wsq_bytes = (size_t)COUT * CIN * 4;           //  1,048,576
  const size_t rsig_bytes = (size_t)NB * COUT * 4;           //     32,768
  const size_t part_bytes = (size_t)NPIX * COUT * 2;         // 16,777,216
  const size_t base_bytes = xpad_bytes + wB_bytes + wsq_bytes + rsig_bytes;
  __hip_bfloat16* xpad = (__hip_bfloat16*)ws;
  __hip_bfloat16* wB = (__hip_bfloat16*)(ws + xpad_bytes);
  float* wsq = (float*)(ws + xpad_bytes + wB_bytes);
  float* rsig = (float*)(ws + xpad_bytes + wB_bytes + wsq_bytes);
  __hip_bfloat16* pa = (__hip_bfloat16*)(ws + base_bytes);
  __hip_bfloat16* pb = (__hip_bfloat16*)(ws + base_bytes + part_bytes);
  const bool fits2 = ws_size >= base_bytes + 2 * part_bytes;

  halo_zero_kernel<<<NB * 132, 256, 0, stream>>>(xpad);
  pack_w_kernel<<<(COUT * CIN) / 256, 256, 0, stream>>>(w, wB, wsq);
  modulate_kernel<<<NB * 32, 256, 0, stream>>>(x, s, xpad);
  calc_rsig_kernel<<<(NB * COUT) / 4, 256, 0, stream>>>(s, wsq, rsig);

  const int mblocks = (NPIX * COUT / 8) / 256;   // 4096
  if (fits2) {
    conv_gemm_kernel<<<dim3(NPIX / 256, COUT / 128, 2), 256, 0, stream>>>(
        wB, xpad, rsig, out, pa, pb);
    merge2_kernel<<<mblocks, 256, 0, stream>>>(out, pa, pb);
  } else {
    conv_gemm_kernel<<<dim3(NPIX / 256, COUT / 128, 2), 256, 0, stream>>>(
        wB, xpad, rsig, out, nullptr, pa);
    merge1_kernel<<<mblocks, 256, 0, stream>>>(out, pa);
  }
}

// Round 16
// 103.234 us; speedup vs baseline: 1.6287x; 1.1226x over previous
//
#include <hip/hip_runtime.h>
#include <hip/hip_bf16.h>

// Modulated conv2d (StyleGAN2) on MI355X.
// out[b,o] = rsig[b,o] * conv(s[b,:]*x[b,:], W*SCALE)   (shared weights)
// rsig[b,o] = 1/sqrt(sum_i s[b,i]^2 * wsq[o,i] + 1e-8)
// Conv as implicit GEMM: D[o][p] = sum_k Wb[o][k] * Xcl[p][k].
//
// R16 = consolidation: best conv x best tail, never previously combined.
//  - conv = R6's exact body (BK=64, single-buffer 48KB LDS, plain
//    2x __syncthreads per K-tile, 256 thr / 4 waves 2Mx2N, per-wave 64x128,
//    z-split x2 -> 512 blocks = 2 independent blocks/CU). Measured five
//    rounds at 73.7us / MfmaUtil 46% / 0 conflicts — beats every pipelined
//    variant (R2/R4/R7/R11/R14/R15) and every A-path variant (R3/R9/R12).
//    R15's clean experiment (conflicts 7.08M->0, time unchanged) proved the
//    critical path is per-tile stage/barrier machinery, not LDS reads —
//    schedule engineering is exhausted at this shape.
//  - tail = R10's verified pieces: halo-only zero (no 19MB memset), bf16
//    partials for BOTH z-halves (conv z0 write 33.5->16.8MB), merge2
//    (134MB total vs merge1's 168MB). Fallback merge1 if ws is small.

typedef __attribute__((ext_vector_type(4))) float f32x4;
typedef __attribute__((ext_vector_type(8))) short bf16x8;

#define NB    16
#define CIN   512
#define COUT  512
#define KTOT  4608           // CIN * 9
#define NPIX  (NB * 32 * 32) // 16384
#define KTPZ  36             // K64-tiles per z-half

__device__ __forceinline__ void gload_lds16(const void* g, void* l) {
  __builtin_amdgcn_global_load_lds(
      (__attribute__((address_space(1))) void*)(g),
      (__attribute__((address_space(3))) void*)(l), 16, 0, 0);
}

__device__ __forceinline__ float bf16bits_to_f32(short v) {
  return __uint_as_float(((unsigned)(unsigned short)v) << 16);
}

// ---- kernel 1: pack weights (bf16, [o][tap*512+ci]) + wsq ----
__global__ __launch_bounds__(256) void pack_w_kernel(
    const float* __restrict__ w, __hip_bfloat16* __restrict__ wB,
    float* __restrict__ wsq) {
  const int idx = blockIdx.x * 256 + threadIdx.x;   // = o*512 + ci
  const int o = idx >> 9, ci = idx & 511;
  const float* wp = w + (size_t)idx * 9;
  const float WSCALE = 0.014731391274719739f;       // 1/sqrt(512*9)
  float sum = 0.f;
#pragma unroll
  for (int t = 0; t < 9; ++t) {
    float v = wp[t] * WSCALE;
    sum += v * v;
    wB[(size_t)o * KTOT + t * 512 + ci] = __float2bfloat16(v);
  }
  wsq[idx] = sum;
}

// ---- kernel 2: rsig[b][o], one wave per (b,o) ----
__global__ __launch_bounds__(256) void calc_rsig_kernel(
    const float* __restrict__ s, const float* __restrict__ wsq,
    float* __restrict__ rsig) {
  const int wid = blockIdx.x * 4 + (threadIdx.x >> 6); // b*512 + o
  const int lane = threadIdx.x & 63;
  const int b = wid >> 9, o = wid & 511;
  const float* sp = s + b * 512;
  const float* wp = wsq + o * 512;
  float sum = 0.f;
#pragma unroll
  for (int i = 0; i < 8; ++i) {
    float sv = sp[lane + i * 64];
    sum += sv * sv * wp[lane + i * 64];
  }
#pragma unroll
  for (int off = 32; off > 0; off >>= 1) sum += __shfl_down(sum, off, 64);
  if (lane == 0) rsig[wid] = 1.0f / sqrtf(sum + 1e-8f);
}

// ---- kernel 3: modulate + NCHW -> padded channels-last bf16 ----
__global__ __launch_bounds__(256) void modulate_kernel(
    const float* __restrict__ x, const float* __restrict__ s,
    __hip_bfloat16* __restrict__ xpad) {
  const int by = blockIdx.x;            // b*32 + y
  const int b = by >> 5, y = by & 31;
  __shared__ __attribute__((aligned(16))) __hip_bfloat16 tile[32][72];
  const int tid = threadIdx.x;
  const int xc = tid & 31;
  const int cr0 = tid >> 5;
  const float* xrow = x + ((size_t)b * 512 * 32 + y) * 32;
  const float* sb = s + b * 512;
  __hip_bfloat16* orow = xpad + (size_t)((b * 34 + y + 1) * 34) * 512;

  for (int ci0 = 0; ci0 < 512; ci0 += 64) {
#pragma unroll
    for (int r = 0; r < 8; ++r) {
      const int cir = r * 8 + cr0;
      const int ci = ci0 + cir;
      float v = xrow[(size_t)ci * 1024 + xc] * sb[ci];
      tile[xc][cir] = __float2bfloat16(v);
    }
    __syncthreads();
    const int xcw = tid >> 3, vec = tid & 7;
    bf16x8 v = *(const bf16x8*)&tile[xcw][vec * 8];
    *(bf16x8*)(orow + (size_t)(xcw + 1) * 512 + ci0 + vec * 8) = v;
    __syncthreads();
  }
}

// ---- kernel 3b: zero only the halo of xpad ----
__global__ __launch_bounds__(256) void halo_zero_kernel(
    __hip_bfloat16* __restrict__ xpad) {
  const int sb = blockIdx.x;           // b*132 + site
  const int b = sb / 132, s = sb - b * 132;
  int y, x;
  if (s < 34)       { y = 0;        x = s; }
  else if (s < 68)  { y = 33;       x = s - 34; }
  else if (s < 100) { y = s - 67;   x = 0; }
  else              { y = s - 99;   x = 33; }
  unsigned* p = (unsigned*)(xpad + (size_t)((b * 34 + y) * 34 + x) * 512);
  p[threadIdx.x] = 0u;   // 256 x 4B = 512 bf16
}

// ---- kernel 4: implicit-GEMM conv (R6 body), z-split x2 ----
// Block: 128 cout x 256 pix x K2304 (36 K64-tiles). 256 thr, 4 waves 2Mx2N,
// per-wave 64x128 (acc 4x8). LDS: A[128][64] 16KB + B[256][64] 32KB,
// single-buffered, row-major 128B rows, XOR swizzle byte^=((row&7)<<4) on
// staging source chunk + ds_read (rule 21; 0 conflicts measured R1-R13).
__global__ __launch_bounds__(256, 2) void conv_gemm_kernel(
    const __hip_bfloat16* __restrict__ wB,    // [512][4608]
    const __hip_bfloat16* __restrict__ xpad,  // [16][34][34][512]
    const float* __restrict__ rsig,           // [16][512]
    float* __restrict__ out,                  // f32 out (fallback, z=0)
    __hip_bfloat16* __restrict__ p0,          // bf16 partial z=0 (or null)
    __hip_bfloat16* __restrict__ p1) {        // bf16 partial z=1
  __shared__ __attribute__((aligned(16))) __hip_bfloat16 ldsA[128 * 64];
  __shared__ __attribute__((aligned(16))) __hip_bfloat16 ldsB[256 * 64];

  const int tid = threadIdx.x;
  const int wv = tid >> 6, lane = tid & 63, l15 = lane & 15;
  const int bo0 = blockIdx.y << 7;   // cout block (128)
  const int bp0 = blockIdx.x << 8;   // pixel block (256; 256 | 1024 per image)
  const int z = blockIdx.z;          // K-half
  const int bimg = blockIdx.x >> 2;
  const int wr = wv >> 1, wc = wv & 1;

  // Staging source offsets (pre-swizzled chunk within row; rule 21).
  int gA[4];   // + ktg*64 per tile
#pragma unroll
  for (int r = 0; r < 4; ++r) {
    const int c = r * 256 + tid, row = c >> 3, sc = (c & 7) ^ (row & 7);
    gA[r] = (bo0 + row) * KTOT + sc * 8;
  }
  int gB[8];   // + tapoff*512 + ci0 per tile
#pragma unroll
  for (int r = 0; r < 8; ++r) {
    const int c = r * 256 + tid, row = c >> 3, sc = (c & 7) ^ (row & 7);
    const int p = bp0 + row, b = p >> 10, rem = p & 1023, y = rem >> 5,
              xx = rem & 31;
    gB[r] = ((b * 34 + y) * 34 + xx) * 512 + sc * 8;
  }

  f32x4 acc[4][8];
#pragma unroll
  for (int mi = 0; mi < 4; ++mi)
#pragma unroll
    for (int ni = 0; ni < 8; ++ni) acc[mi][ni] = f32x4{0.f, 0.f, 0.f, 0.f};

  const int kb0 = (lane >> 4) << 4;   // byte base of this lane's k-slot

#pragma unroll 1
  for (int kt = 0; kt < KTPZ; ++kt) {
    const int ktg = z * KTPZ + kt;
    const int tap = ktg >> 3;
    const int xoff = (tap + 31 * (tap / 3)) * 512 + ((ktg & 7) << 6);
    // ---- stage tile (12 x 16B per thread) ----
#pragma unroll
    for (int r = 0; r < 4; ++r)
      gload_lds16(wB + (size_t)(gA[r] + (ktg << 6)),
                  (char*)ldsA + (r * 256 + tid) * 16);
#pragma unroll
    for (int r = 0; r < 8; ++r)
      gload_lds16(xpad + (size_t)(gB[r] + xoff),
                  (char*)ldsB + (r * 256 + tid) * 16);
    __syncthreads();   // drains vmcnt -> staged data visible

    bf16x8 af[4][2];
#pragma unroll
    for (int mi = 0; mi < 4; ++mi) {
      const int row = (wr << 6) + (mi << 4) + l15;
      const int swz = (row & 7) << 4;
      af[mi][0] = *(const bf16x8*)((const char*)ldsA + row * 128 + (kb0 ^ swz));
      af[mi][1] = *(const bf16x8*)((const char*)ldsA + row * 128 + ((64 | kb0) ^ swz));
    }
    {
      bf16x8 bv[8];
#pragma unroll
      for (int ni = 0; ni < 8; ++ni) {
        const int row = (wc << 7) + (ni << 4) + l15;
        bv[ni] = *(const bf16x8*)((const char*)ldsB + row * 128 +
                                  (kb0 ^ ((row & 7) << 4)));
      }
#pragma unroll
      for (int mi = 0; mi < 4; ++mi)
#pragma unroll
        for (int ni = 0; ni < 8; ++ni)
          acc[mi][ni] = __builtin_amdgcn_mfma_f32_16x16x32_bf16(
              af[mi][0], bv[ni], acc[mi][ni], 0, 0, 0);
    }
    {
      bf16x8 bv[8];
#pragma unroll
      for (int ni = 0; ni < 8; ++ni) {
        const int row = (wc << 7) + (ni << 4) + l15;
        bv[ni] = *(const bf16x8*)((const char*)ldsB + row * 128 +
                                  ((64 | kb0) ^ ((row & 7) << 4)));
      }
#pragma unroll
      for (int mi = 0; mi < 4; ++mi)
#pragma unroll
        for (int ni = 0; ni < 8; ++ni)
          acc[mi][ni] = __builtin_amdgcn_mfma_f32_16x16x32_bf16(
              af[mi][1], bv[ni], acc[mi][ni], 0, 0, 0);
    }
    __syncthreads();   // all reads done before next stage overwrites
  }

  // Epilogue: scale by rsig -> bf16 partial pz (f32 out if p0==null && z==0).
  // C/D: col(=p)=lane&15, row(=o)=(lane>>4)*4+r
  __hip_bfloat16* pz = z ? p1 : p0;
  const bool f32path = (p0 == nullptr) && (z == 0);
#pragma unroll
  for (int mi = 0; mi < 4; ++mi) {
    const int o = bo0 + (wr << 6) + (mi << 4) + ((lane >> 4) << 2);
    const f32x4 rs = *(const f32x4*)(rsig + (bimg << 9) + o);
#pragma unroll
    for (int ni = 0; ni < 8; ++ni) {
      const int p = bp0 + (wc << 7) + (ni << 4) + l15;
      const int prem = p & 1023;
#pragma unroll
      for (int r = 0; r < 4; ++r) {
        const float v = acc[mi][ni][r] * rs[r];
        const size_t oidx = ((size_t)((bimg << 9) + o + r)) * 1024 + prem;
        if (f32path) out[oidx] = v;
        else pz[oidx] = __float2bfloat16(v);
      }
    }
  }
}

// ---- kernel 5a: merge out = p0 + p1 ----
__global__ __launch_bounds__(256) void merge2_kernel(
    float* __restrict__ out, const __hip_bfloat16* __restrict__ p0,
    const __hip_bfloat16* __restrict__ p1) {
  const size_t i = (size_t)blockIdx.x * 256 + threadIdx.x;
  const bf16x8 a = ((const bf16x8*)p0)[i];
  const bf16x8 b = ((const bf16x8*)p1)[i];
  f32x4 o0, o1;
#pragma unroll
  for (int j = 0; j < 4; ++j) {
    o0[j] = bf16bits_to_f32(a[j]) + bf16bits_to_f32(b[j]);
    o1[j] = bf16bits_to_f32(a[4 + j]) + bf16bits_to_f32(b[4 + j]);
  }
  ((f32x4*)out)[2 * i] = o0;
  ((f32x4*)out)[2 * i + 1] = o1;
}

// ---- kernel 5b: fallback merge out += p1 ----
__global__ __launch_bounds__(256) void merge1_kernel(
    float* __restrict__ out, const __hip_bfloat16* __restrict__ p1) {
  const size_t i = (size_t)blockIdx.x * 256 + threadIdx.x;
  f32x4* o4 = (f32x4*)out + 2 * i;
  f32x4 a = o4[0], b = o4[1];
  const bf16x8 pv = ((const bf16x8*)p1)[i];
#pragma unroll
  for (int j = 0; j < 4; ++j) {
    a[j] += bf16bits_to_f32(pv[j]);
    b[j] += bf16bits_to_f32(pv[4 + j]);
  }
  o4[0] = a;
  o4[1] = b;
}

extern "C" void kernel_launch(void* const* d_in, const int* in_sizes, int n_in,
                              void* d_out, int out_size, void* d_ws,
                              size_t ws_size, hipStream_t stream) {
  const float* x = (const float*)d_in[0];   // [16,512,32,32]
  const float* s = (const float*)d_in[1];   // [16,512]
  const float* w = (const float*)d_in[2];   // [512,512,3,3]
  float* out = (float*)d_out;               // [16,512,32,32] f32

  char* ws = (char*)d_ws;
  const size_t xpad_bytes = (size_t)NB * 34 * 34 * 512 * 2;  // 18,939,904
  const size_t wB_bytes = (size_t)COUT * KTOT * 2;           //  4,718,592
  const size_t wsq_bytes = (size_t)COUT * CIN * 4;           //  1,048,576
  const size_t rsig_bytes = (size_t)NB * COUT * 4;           //     32,768
  const size_t part_bytes = (size_t)NPIX * COUT * 2;         // 16,777,216
  const size_t base_bytes = xpad_bytes + wB_bytes + wsq_bytes + rsig_bytes;
  __hip_bfloat16* xpad = (__hip_bfloat16*)ws;
  __hip_bfloat16* wB = (__hip_bfloat16*)(ws + xpad_bytes);
  float* wsq = (float*)(ws + xpad_bytes + wB_bytes);
  float* rsig = (float*)(ws + xpad_bytes + wB_bytes + wsq_bytes);
  __hip_bfloat16* pa = (__hip_bfloat16*)(ws + base_bytes);
  __hip_bfloat16* pb = (__hip_bfloat16*)(ws + base_bytes + part_bytes);
  const bool fits2 = ws_size >= base_bytes + 2 * part_bytes;

  halo_zero_kernel<<<NB * 132, 256, 0, stream>>>(xpad);
  pack_w_kernel<<<(COUT * CIN) / 256, 256, 0, stream>>>(w, wB, wsq);
  modulate_kernel<<<NB * 32, 256, 0, stream>>>(x, s, xpad);
  calc_rsig_kernel<<<(NB * COUT) / 4, 256, 0, stream>>>(s, wsq, rsig);

  const int mblocks = (NPIX * COUT / 8) / 256;   // 4096
  if (fits2) {
    conv_gemm_kernel<<<dim3(NPIX / 256, COUT / 128, 2), 256, 0, stream>>>(
        wB, xpad, rsig, out, pa, pb);
    merge2_kernel<<<mblocks, 256, 0, stream>>>(out, pa, pb);
  } else {
    conv_gemm_kernel<<<dim3(NPIX / 256, COUT / 128, 2), 256, 0, stream>>>(
        wB, xpad, rsig, out, nullptr, pa);
    merge1_kernel<<<mblocks, 256, 0, stream>>>(out, pa);
  }
}